// Round 25
// baseline (149.244 us; speedup 1.0000x reference)
//
#include <hip/hip_runtime.h>
#include <hip/hip_bf16.h>

// ---------------------------------------------------------------------------
// DropBlock fused dual-conv, LIST-COMPACTED implicit GEMM (half FLOPs).
// NEW conv: WAVE-PER-BLOCK, ZERO-BARRIER. 64 thr = 1 wave per block; tile =
// 112 list rows x 64 branch channels; wave-private LDS double buffer
// (2 x 11264 B = 22528 -> 7 blocks/CU = 7 independent streams, m114 overlap).
// No s_barrier in the K-loop: per-wave vmcnt/lgkmcnt only.
//   Per K-tile (72 of BK=32): STG(t+1) [11 gll16: A 7 + B 4] ->
//     ds av0(4)+bv(4)+av1(3) -> LGKM(3) -> MM mh0 (16) -> LGKM(0) ->
//     MM mh1 (12) -> VM(0).
//   WAR within wave: t-1's ds reads drained at its LGKM(0) (program order)
//     before t+1's stage into the same slot issues.
// Grid 1800 = 8x225 XCD-bijective; vt = lb>>2 (112-row tile), wq = lb&3
// (64-ch quarter); ragged tails clamp to cnt-1 (dup stores, benign).
// prep = round-23 passing version, byte-identical (xt transform, wt blocks
// [72t][4nq][128row][4ps][8jj], chunk-256 m-ordered lists).
// ws: [0,4) cntB | [4,8) cntA | [65536,+29491200) xt bf16 [64][30][30][256]
//     | [29556736,+2359296) wt | [31916032,+200704) listA
//     | [32116736,+200704) listB
// ---------------------------------------------------------------------------

typedef __bf16  bf16x8 __attribute__((ext_vector_type(8)));
typedef float   f32x4  __attribute__((ext_vector_type(4)));
typedef short   short8 __attribute__((ext_vector_type(8)));
typedef unsigned int u32;
typedef unsigned short u16;

#define XT_OFF     65536
#define WT_OFF     29556736
#define LISTA_OFF  31916032
#define LISTB_OFF  32116736
#define SLOT       11264

__device__ __forceinline__ u16 f2bf(float v) {
    u32 u = __float_as_uint(v);
    u32 r = (u + 0x7FFFu + ((u >> 16) & 1u)) >> 16;
    return (u16)r;
}

__device__ __forceinline__ void gll16(const void* g, void* l) {
    __builtin_amdgcn_global_load_lds(
        (const __attribute__((address_space(1))) u32*)g,
        (__attribute__((address_space(3))) u32*)l, 16, 0, 0);
}

// ---------------- fused prep: xt transform + wt blocks + mask/lists --------
__global__ void prep_kernel(const float* __restrict__ x,
                            const float* __restrict__ wl,
                            const float* __restrict__ wp,
                            const float* __restrict__ mu,
                            u16* __restrict__ xt, u16* __restrict__ wt,
                            int* __restrict__ listA, int* __restrict__ listB,
                            int* __restrict__ cntB, int* __restrict__ cntA) {
    int b = blockIdx.x, tid = threadIdx.x;
    if (b < 1920) {                                   // ---- xt: 64*30 rows
        int n = b / 30, oh = b % 30;
        u16* row = xt + (size_t)(n * 30 + oh) * 30 * 256;
        if (oh == 0 || oh == 29) {                    // halo rows: full zero
            u32* r32 = (u32*)row;
            #pragma unroll
            for (int i = 0; i < 15; ++i) r32[i * 256 + tid] = 0;
            return;
        }
        __shared__ u16 sm[7168];                      // [28 w][256 c]
        int h = oh - 1;
        const float* src = x + ((size_t)(n * 256 + tid) * 28 + h) * 28;
        float f[28];
        #pragma unroll
        for (int q = 0; q < 7; ++q) {
            float4 v = *(const float4*)(src + q * 4);
            f[q * 4 + 0] = v.x; f[q * 4 + 1] = v.y;
            f[q * 4 + 2] = v.z; f[q * 4 + 3] = v.w;
        }
        #pragma unroll
        for (int w = 0; w < 28; ++w)
            sm[w * 256 + tid] = f2bf(f[w]);           // 2-way banks: free
        __syncthreads();
        u32* r32 = (u32*)row;
        if (tid < 128) r32[tid] = 0;                  // halo col ow=0
        else           r32[29 * 128 + (tid - 128)] = 0;   // halo col ow=29
        const u32* s32 = (const u32*)sm;
        u32* dst = r32 + 128;                         // ow=1..28 contiguous
        #pragma unroll
        for (int k = 0; k < 14; ++k)                  // 3584 u32 coalesced
            dst[k * 256 + tid] = s32[k * 256 + tid];
    } else if (b < 2048) {                            // ---- wt (coalesced)
        __shared__ u16 wsm[9216];                     // [4 rl][2304 = c*9+kk]
        int wb = b - 1920;                            // 0..127
        int bn = wb >> 6, rowg = (wb & 63) * 4;       // rows rowg..rowg+3
        const float* wsrc = (bn ? wp : wl) + (size_t)rowg * 2304;
        const f32x4* s4 = (const f32x4*)wsrc;         // 2304 float4
        #pragma unroll
        for (int i = 0; i < 9; ++i) {
            int q = i * 256 + tid;
            f32x4 v = s4[q];
            #pragma unroll
            for (int cmp = 0; cmp < 4; ++cmp)
                wsm[q * 4 + cmp] = f2bf(v[cmp]);
        }
        __syncthreads();
        u32* wo = (u32*)wt;
        #pragma unroll
        for (int w = 0; w < 18; ++w) {                // 4608 u32 per block
            int idx = w * 256 + tid;
            int jjp = idx & 3, ps = (idx >> 2) & 3;
            int tt = idx >> 4;                        // 0..287
            int t = tt % 72, rl = tt / 72;
            int row = rowg + rl;                      // 0..255
            int row128 = row & 127, nh = row >> 7;
            int c0 = (t & 7) * 32 + ((ps ^ ((row >> 1) & 3)) << 3) + jjp * 2;
            int e0 = rl * 2304 + c0 * 9 + (t >> 3);
            u32 val = (u32)wsm[e0] | ((u32)wsm[e0 + 9] << 16);
            wo[(size_t)(t * 4 + bn * 2 + nh) * 2048 + row128 * 16 + ps * 4 + jjp]
                = val;
        }
    } else {                                          // ---- mask + list build
        __shared__ int lsum[4];
        __shared__ int basB, basA;
        int m = (b - 2048) * 256 + tid;               // 196*256 exact
        int n = m / 784, rem = m % 784;
        int h = rem / 28, w = rem % 28;
        const float g = (float)(0.1 / 49.0);
        const float* un = mu + n * 784;
        int p = 0;
        for (int dy = -3; dy <= 3; ++dy) {
            int hh = h + dy;
            if (hh < 0 || hh >= 28) continue;
            for (int dx = -3; dx <= 3; ++dx) {
                int ww = w + dx;
                if (ww < 0 || ww >= 28) continue;
                p |= (un[hh * 28 + ww] < g) ? 1 : 0;
            }
        }
        unsigned long long ball = __ballot(p);
        int wid = tid >> 6, ln = tid & 63;
        if (ln == 0) lsum[wid] = __popcll(ball);
        __syncthreads();
        if (tid == 0) {
            int tB = lsum[0] + lsum[1] + lsum[2] + lsum[3];
            basB = atomicAdd(cntB, tB);
            basA = atomicAdd(cntA, 256 - tB);
        }
        __syncthreads();
        int offB = 0, offA = 0;
        for (int i = 0; i < wid; ++i) { offB += lsum[i]; offA += 64 - lsum[i]; }
        int rank1 = __popcll(ball & ((1ULL << ln) - 1));
        int rank0 = ln - rank1;
        if (p) listB[basB + offB + rank1] = m;
        else   listA[basA + offA + rank0] = m;
    }
}

// ---------------- wave-per-block zero-barrier implicit-GEMM conv -----------
__global__ __launch_bounds__(64, 2)
void conv_kernel(const char* __restrict__ xt,    // bf16 padded NHWC (bytes)
                 const char* __restrict__ wt,    // bf16 swizzled blocks (bytes)
                 const int* __restrict__ listA,
                 const int* __restrict__ listB,
                 const int* __restrict__ dropped,   // = cntB
                 float* __restrict__ out) {
    __shared__ char smem[22528];                  // 2 slots x 11264
    const int lane = threadIdx.x;                 // 64 threads = 1 wave
    const int lb = (blockIdx.x & 7) * 225 + (blockIdx.x >> 3);  // 1800 = 8*225
    const int vt = lb >> 2;                  // 112-row virtual tile
    const int wq = lb & 3;                   // 64-ch quarter of the branch
    const int cB = *dropped;
    const int cA = 50176 - cB;
    const int naT = (cA + 111) / 112;
    const int nbT = (cB + 111) / 112;
    if (vt >= naT + nbT) return;             // block-uniform exit
    const int branch = (vt >= naT) ? 1 : 0;
    const int tix = branch ? (vt - naT) : vt;
    const int cnt = branch ? cB : cA;
    const int* lst = branch ? listB : listA;
    const int nq = branch * 2 + (wq >> 1);   // wt 128-row block
    const int qoff = (wq & 1) * 4096;        // 64-row half within block
    const int lane15 = lane & 15, grp = lane >> 4;

    // --- A staging source bases (7 gll16 ops, 16 rows each) ---
    long pbA[7];
    {
        int swz = ((lane & 3) ^ ((lane >> 3) & 3)) << 4;
        #pragma unroll
        for (int i = 0; i < 7; ++i) {
            int idx = tix * 112 + i * 16 + (lane >> 2);
            if (idx >= cnt) idx = cnt - 1;   // ragged-tail clamp (dup rows)
            int m = lst[idx];
            int n = m / 784, rem = m % 784;
            pbA[i] = (long)(((n * 30 + rem / 28 + 1) * 30 + (rem % 28 + 1)) * 512
                            + swz);
        }
    }

    f32x4 acc[7][4];
    #pragma unroll
    for (int i = 0; i < 7; ++i)
        #pragma unroll
        for (int j = 0; j < 4; ++j)
            acc[i][j] = (f32x4){0.f, 0.f, 0.f, 0.f};

    const int so  = (grp ^ ((lane15 >> 1) & 3)) << 4;    // read swizzle
    const int arb = (lane15 << 6) + so;                  // A base in slot
    const int brb = 7168 + (lane15 << 6) + so;           // B base in slot

#define AON(TC) ((long)((TC) >> 3) / 3 * 15360 + (long)(((TC) >> 3) % 3) * 512 \
                 - 15872 + (long)(((TC) & 7) << 6))
#define STG(TC, SL) { char* sd_ = smem + (SL) * SLOT;                       \
        const long ao_ = AON(TC);                                           \
        _Pragma("unroll")                                                   \
        for (int i_ = 0; i_ < 7; ++i_)                                      \
            gll16(xt + pbA[i_] + ao_, sd_ + i_ * 1024 + (lane << 4));       \
        const char* wb_ = wt + ((size_t)((TC) * 4 + nq) << 13) + qoff;      \
        _Pragma("unroll")                                                   \
        for (int j_ = 0; j_ < 4; ++j_)                                      \
            gll16(wb_ + j_ * 1024 + (lane << 4),                            \
                  sd_ + 7168 + j_ * 1024 + (lane << 4)); }
#define DS_AV0(dst, SL) { const char* sb_ = smem + (SL) * SLOT;             \
        _Pragma("unroll")                                                   \
        for (int fm = 0; fm < 4; ++fm)                                      \
            dst[fm] = *(const bf16x8*)(sb_ + arb + (fm << 10)); }
#define DS_AV1(dst, SL) { const char* sb_ = smem + (SL) * SLOT + 4096;      \
        _Pragma("unroll")                                                   \
        for (int fm = 0; fm < 3; ++fm)                                      \
            dst[fm] = *(const bf16x8*)(sb_ + arb + (fm << 10)); }
#define DS_BV(dst, SL) { const char* sb_ = smem + (SL) * SLOT;              \
        _Pragma("unroll")                                                   \
        for (int fn = 0; fn < 4; ++fn)                                      \
            dst[fn] = *(const bf16x8*)(sb_ + brb + (fn << 10)); }
#define MM(A0_, NF, AV, BV) { __builtin_amdgcn_s_setprio(1);                \
        _Pragma("unroll")                                                   \
        for (int fm = 0; fm < (NF); ++fm)                                   \
            _Pragma("unroll")                                               \
            for (int fn = 0; fn < 4; ++fn)                                  \
                acc[(A0_)+fm][fn] = __builtin_amdgcn_mfma_f32_16x16x32_bf16( \
                    AV[fm], BV[fn], acc[(A0_)+fm][fn], 0, 0, 0);            \
        __builtin_amdgcn_s_setprio(0); }
#define LGKM(N) { asm volatile("s_waitcnt lgkmcnt(" #N ")" ::: "memory");   \
                  __builtin_amdgcn_sched_barrier(0); }
#define VM0     { asm volatile("s_waitcnt vmcnt(0)" ::: "memory");          \
                  __builtin_amdgcn_sched_barrier(0); }

    bf16x8 av0[4], av1[3], bv[4];

    // --- prologue: stage tile 0 into slot 0 (no barriers anywhere) ---
    STG(0, 0);
    VM0;

    for (int t = 0; t < 72; ++t) {
        const int sc = t & 1, ss = sc ^ 1;
        if (t < 71) STG(t + 1, ss);
        DS_AV0(av0, sc);
        DS_BV(bv, sc);
        DS_AV1(av1, sc);
        LGKM(3);                    // av0+bv ready; av1 still landing
        MM(0, 4, av0, bv);
        LGKM(0);                    // av1 ready
        MM(4, 3, av1, bv);
        VM0;                        // tile t+1 staged & landed
    }

    // --- epilogue: single-wave LDS transpose -> coalesced scaled stores ---
    float scale = 50176.0f / (float)(50176 - cB);
    float* ep = (float*)smem;                    // [32][65] f32 scratch
    #pragma unroll
    for (int rr = 0; rr < 4; ++rr) {
        const int r2 = rr & 1;        // 32-channel half of this quarter's 64
        const int mh = rr >> 1;       // m half: 0 -> 64 pos, 1 -> 48 pos
        const int nf = mh ? 3 : 4;
        for (int fm2 = 0; fm2 < nf; ++fm2)
            #pragma unroll
            for (int f2 = 0; f2 < 2; ++f2)
                #pragma unroll
                for (int j = 0; j < 4; ++j)
                    ep[(f2 * 16 + lane15) * 65 + fm2 * 16 + grp * 4 + j] =
                        acc[mh * 4 + fm2][r2 * 2 + f2][j];
        LGKM(0);                      // ds_writes landed (single wave)
        {
            int gidx = tix * 112 + mh * 64 + lane;
            if ((mh == 0 || lane < 48) && gidx < cnt) {
                int m = lst[gidx];
                int n = m / 784, rem = m % 784;
                size_t ob = (size_t)n * 200704 + rem;
                #pragma unroll
                for (int ch = 0; ch < 32; ++ch) {
                    int c = wq * 64 + r2 * 32 + ch;
                    out[ob + (size_t)c * 784] = ep[ch * 65 + lane] * scale;
                }
            }
        }
        LGKM(0);                      // ds_reads done before next overwrite
    }
#undef AON
#undef STG
#undef DS_AV0
#undef DS_AV1
#undef DS_BV
#undef MM
#undef LGKM
#undef VM0
}

// ---------------------------------------------------------------------------
extern "C" void kernel_launch(void* const* d_in, const int* in_sizes, int n_in,
                              void* d_out, int out_size, void* d_ws, size_t ws_size,
                              hipStream_t stream) {
    const float* x  = (const float*)d_in[0];
    const float* wl = (const float*)d_in[1];
    const float* wp = (const float*)d_in[2];
    const float* mu = (const float*)d_in[3];
    float* out = (float*)d_out;
    char* ws = (char*)d_ws;

    int* cntB = (int*)ws;                     // = dropped
    int* cntA = (int*)(ws + 4);
    u16* xt = (u16*)(ws + XT_OFF);
    u16* wt = (u16*)(ws + WT_OFF);
    int* listA = (int*)(ws + LISTA_OFF);
    int* listB = (int*)(ws + LISTB_OFF);

    hipMemsetAsync(ws, 0, 8, stream);

    prep_kernel<<<2244, 256, 0, stream>>>(x, wl, wp, mu, xt, wt,
                                          listA, listB, cntB, cntA);
    conv_kernel<<<1800, 64, 0, stream>>>((const char*)xt, (const char*)wt,
                                         listA, listB, cntB, out);
}

// Round 26
// 102.062 us; speedup vs baseline: 1.4623x; 1.4623x over previous
//
#include <hip/hip_runtime.h>
#include <hip/hip_bf16.h>

// ---------------------------------------------------------------------------
// DropBlock fused dual-conv, LIST-COMPACTED implicit GEMM (half FLOPs).
// FINAL = round-23 best (102.2 us total). Conv core: 224x128 tiles, 456
// blocks (8x57 XCD-bijective), 2 blk/CU, depth-1 VM0+BAR, split LGKM,
// setprio, 16x16x32 MFMA. Lists: chunk-256 m-ordered compaction.
// wt transform: coalesced float4 stage -> LDS -> scatter to
// [72t][4 nq][128 row][4 ps][8 jj] XOR-swizzled blocks.
// ws: [0,4) cntB | [4,8) cntA | [65536,+29491200) xt bf16 [64][30][30][256]
//     | [29556736,+2359296) wt | [31916032,+200704) listA
//     | [32116736,+200704) listB
// ---------------------------------------------------------------------------

typedef __bf16  bf16x8 __attribute__((ext_vector_type(8)));
typedef float   f32x4  __attribute__((ext_vector_type(4)));
typedef short   short8 __attribute__((ext_vector_type(8)));
typedef unsigned int u32;
typedef unsigned short u16;

#define XT_OFF     65536
#define WT_OFF     29556736
#define LISTA_OFF  31916032
#define LISTB_OFF  32116736
#define SLOT       22528

__device__ __forceinline__ u16 f2bf(float v) {
    u32 u = __float_as_uint(v);
    u32 r = (u + 0x7FFFu + ((u >> 16) & 1u)) >> 16;
    return (u16)r;
}

__device__ __forceinline__ void gll16(const void* g, void* l) {
    __builtin_amdgcn_global_load_lds(
        (const __attribute__((address_space(1))) u32*)g,
        (__attribute__((address_space(3))) u32*)l, 16, 0, 0);
}

// ---------------- fused prep: xt transform + wt transform + mask/lists -----
__global__ void prep_kernel(const float* __restrict__ x,
                            const float* __restrict__ wl,
                            const float* __restrict__ wp,
                            const float* __restrict__ mu,
                            u16* __restrict__ xt, u16* __restrict__ wt,
                            int* __restrict__ listA, int* __restrict__ listB,
                            int* __restrict__ cntB, int* __restrict__ cntA) {
    int b = blockIdx.x, tid = threadIdx.x;
    if (b < 1920) {                                   // ---- xt: 64*30 rows
        int n = b / 30, oh = b % 30;
        u16* row = xt + (size_t)(n * 30 + oh) * 30 * 256;
        if (oh == 0 || oh == 29) {                    // halo rows: full zero
            u32* r32 = (u32*)row;
            #pragma unroll
            for (int i = 0; i < 15; ++i) r32[i * 256 + tid] = 0;
            return;
        }
        __shared__ u16 sm[7168];                      // [28 w][256 c]
        int h = oh - 1;
        const float* src = x + ((size_t)(n * 256 + tid) * 28 + h) * 28;
        float f[28];
        #pragma unroll
        for (int q = 0; q < 7; ++q) {
            float4 v = *(const float4*)(src + q * 4);
            f[q * 4 + 0] = v.x; f[q * 4 + 1] = v.y;
            f[q * 4 + 2] = v.z; f[q * 4 + 3] = v.w;
        }
        #pragma unroll
        for (int w = 0; w < 28; ++w)
            sm[w * 256 + tid] = f2bf(f[w]);           // 2-way banks: free
        __syncthreads();
        u32* r32 = (u32*)row;
        if (tid < 128) r32[tid] = 0;                  // halo col ow=0
        else           r32[29 * 128 + (tid - 128)] = 0;   // halo col ow=29
        const u32* s32 = (const u32*)sm;
        u32* dst = r32 + 128;                         // ow=1..28 contiguous
        #pragma unroll
        for (int k = 0; k < 14; ++k)                  // 3584 u32 coalesced
            dst[k * 256 + tid] = s32[k * 256 + tid];
    } else if (b < 2048) {                            // ---- wt (coalesced)
        // block wb = (bn, rowg): stage 4 rows of wsrc coalesced -> LDS bf16,
        // scatter to wt layout [72t][4 nq][128 row][4 ps][8 jj] (XOR-swizzle).
        __shared__ u16 wsm[9216];                     // [4 rl][2304 = c*9+kk]
        int wb = b - 1920;                            // 0..127
        int bn = wb >> 6, rowg = (wb & 63) * 4;       // rows rowg..rowg+3
        const float* wsrc = (bn ? wp : wl) + (size_t)rowg * 2304;
        const f32x4* s4 = (const f32x4*)wsrc;         // 2304 float4
        #pragma unroll
        for (int i = 0; i < 9; ++i) {
            int q = i * 256 + tid;
            f32x4 v = s4[q];
            #pragma unroll
            for (int cmp = 0; cmp < 4; ++cmp)
                wsm[q * 4 + cmp] = f2bf(v[cmp]);
        }
        __syncthreads();
        u32* wo = (u32*)wt;
        #pragma unroll
        for (int w = 0; w < 18; ++w) {                // 4608 u32 per block
            int idx = w * 256 + tid;
            int jjp = idx & 3, ps = (idx >> 2) & 3;
            int tt = idx >> 4;                        // 0..287
            int t = tt % 72, rl = tt / 72;
            int row = rowg + rl;                      // 0..255
            int row128 = row & 127, nh = row >> 7;
            int c0 = (t & 7) * 32 + ((ps ^ ((row >> 1) & 3)) << 3) + jjp * 2;
            int e0 = rl * 2304 + c0 * 9 + (t >> 3);
            u32 val = (u32)wsm[e0] | ((u32)wsm[e0 + 9] << 16);
            wo[(size_t)(t * 4 + bn * 2 + nh) * 2048 + row128 * 16 + ps * 4 + jjp]
                = val;
        }
    } else {                                          // ---- mask + list build
        __shared__ int lsum[4];
        __shared__ int basB, basA;
        int m = (b - 2048) * 256 + tid;               // 196*256 exact
        int n = m / 784, rem = m % 784;
        int h = rem / 28, w = rem % 28;
        const float g = (float)(0.1 / 49.0);
        const float* un = mu + n * 784;
        int p = 0;
        for (int dy = -3; dy <= 3; ++dy) {
            int hh = h + dy;
            if (hh < 0 || hh >= 28) continue;
            for (int dx = -3; dx <= 3; ++dx) {
                int ww = w + dx;
                if (ww < 0 || ww >= 28) continue;
                p |= (un[hh * 28 + ww] < g) ? 1 : 0;
            }
        }
        unsigned long long ball = __ballot(p);
        int wid = tid >> 6, ln = tid & 63;
        if (ln == 0) lsum[wid] = __popcll(ball);
        __syncthreads();
        if (tid == 0) {
            int tB = lsum[0] + lsum[1] + lsum[2] + lsum[3];
            basB = atomicAdd(cntB, tB);
            basA = atomicAdd(cntA, 256 - tB);
        }
        __syncthreads();
        int offB = 0, offA = 0;
        for (int i = 0; i < wid; ++i) { offB += lsum[i]; offA += 64 - lsum[i]; }
        int rank1 = __popcll(ball & ((1ULL << ln) - 1));
        int rank0 = ln - rank1;
        if (p) listB[basB + offB + rank1] = m;
        else   listA[basA + offA + rank0] = m;
    }
}

// ---------------- list-compacted implicit-GEMM conv + scale (FROZEN) -------
__global__ __launch_bounds__(256, 2)
void conv_kernel(const char* __restrict__ xt,    // bf16 padded NHWC (bytes)
                 const char* __restrict__ wt,    // bf16 swizzled blocks (bytes)
                 const int* __restrict__ listA,
                 const int* __restrict__ listB,
                 const int* __restrict__ dropped,   // = cntB
                 float* __restrict__ out) {
    __shared__ char smem[55296];                  // 2 slots x 22528 (+pad)
    const int tid = threadIdx.x;
    const int lb = (blockIdx.x & 7) * 57 + (blockIdx.x >> 3);  // 456 = 8*57
    const int vt = lb >> 1;                  // virtual tile 0..227
    const int nh = lb & 1;                   // channel half of the branch
    const int cB = *dropped;
    const int cA = 50176 - cB;
    const int naT = (cA + 223) / 224;
    const int nbT = (cB + 223) / 224;
    if (vt >= naT + nbT) return;             // block-uniform exit
    const int branch = (vt >= naT) ? 1 : 0;
    const int tix = branch ? (vt - naT) : vt;
    const int cnt = branch ? cB : cA;
    const int* lst = branch ? listB : listA;
    const int nq = branch * 2 + nh;          // wt quarter
    const int lane = tid & 63, wave = tid >> 6;
    const int lane15 = lane & 15, grp = lane >> 4;
    const int wm = wave >> 1, wn = wave & 1; // per-wave 112 x 64 output

    // --- A staging source bases (via list gather); swizzle folded in ---
    // op i (i<3): rows i*64 + (tid>>2); op 3 (tid<128): rows 192 + (tid>>2)
    long pbA[4];
    {
        int swz = ((tid & 3) ^ ((tid >> 3) & 3)) << 4;
        #pragma unroll
        for (int i = 0; i < 4; ++i) {
            int r = i * 64 + (tid >> 2);
            int idx = tix * 224 + r;
            if (idx >= cnt) idx = cnt - 1;   // ragged-tail clamp (dup rows)
            int m = lst[idx];
            int n = m / 784, rem = m % 784;
            pbA[i] = (long)(((n * 30 + rem / 28 + 1) * 30 + (rem % 28 + 1)) * 512
                            + swz);
        }
    }

    f32x4 acc[7][4];
    #pragma unroll
    for (int i = 0; i < 7; ++i)
        #pragma unroll
        for (int j = 0; j < 4; ++j)
            acc[i][j] = (f32x4){0.f, 0.f, 0.f, 0.f};

    const int so  = (grp ^ ((lane15 >> 1) & 3)) << 4;        // read swizzle
    const int arb = wm * 7168 + (lane15 << 6) + so;          // A base in slot
    const int brb = 14336 + wn * 4096 + (lane15 << 6) + so;  // B base in slot

#define AON(TC) ((long)((TC) >> 3) / 3 * 15360 + (long)(((TC) >> 3) % 3) * 512 \
                 - 15872 + (long)(((TC) & 7) << 6))
#define STG(TC, SL) { char* sd_ = smem + (SL) * SLOT;                       \
        const long ao_ = AON(TC);                                           \
        gll16(xt + pbA[0] + ao_, sd_ + (tid << 4));                         \
        gll16(xt + pbA[1] + ao_, sd_ + 4096 + (tid << 4));                  \
        gll16(xt + pbA[2] + ao_, sd_ + 8192 + (tid << 4));                  \
        if (tid < 128) gll16(xt + pbA[3] + ao_, sd_ + 12288 + (tid << 4));  \
        const char* wb_ = wt + ((size_t)((TC) * 4 + nq) << 13);             \
        gll16(wb_ + (tid << 4), sd_ + 14336 + (tid << 4));                  \
        gll16(wb_ + 4096 + (tid << 4), sd_ + 18432 + (tid << 4)); }
#define DS_AV0(dst, SL) { const char* sb_ = smem + (SL) * SLOT;             \
        _Pragma("unroll")                                                   \
        for (int fm = 0; fm < 4; ++fm)                                      \
            dst[fm] = *(const bf16x8*)(sb_ + arb + (fm << 10)); }
#define DS_AV1(dst, SL) { const char* sb_ = smem + (SL) * SLOT + 4096;      \
        _Pragma("unroll")                                                   \
        for (int fm = 0; fm < 3; ++fm)                                      \
            dst[fm] = *(const bf16x8*)(sb_ + arb + (fm << 10)); }
#define DS_BV(dst, SL) { const char* sb_ = smem + (SL) * SLOT;              \
        _Pragma("unroll")                                                   \
        for (int fn = 0; fn < 4; ++fn)                                      \
            dst[fn] = *(const bf16x8*)(sb_ + brb + (fn << 10)); }
#define MM(A0_, NF, AV, BV) { __builtin_amdgcn_s_setprio(1);                \
        _Pragma("unroll")                                                   \
        for (int fm = 0; fm < (NF); ++fm)                                   \
            _Pragma("unroll")                                               \
            for (int fn = 0; fn < 4; ++fn)                                  \
                acc[(A0_)+fm][fn] = __builtin_amdgcn_mfma_f32_16x16x32_bf16( \
                    AV[fm], BV[fn], acc[(A0_)+fm][fn], 0, 0, 0);            \
        __builtin_amdgcn_s_setprio(0); }
#define LGKM(N) { asm volatile("s_waitcnt lgkmcnt(" #N ")" ::: "memory");   \
                  __builtin_amdgcn_sched_barrier(0); }
#define VM0     { asm volatile("s_waitcnt vmcnt(0)" ::: "memory");          \
                  __builtin_amdgcn_sched_barrier(0); }
#define BAR     asm volatile("s_barrier" ::: "memory")

    bf16x8 av0[4], av1[3], bv[4];

    // --- prologue: stage tile 0 into slot 0 ---
    STG(0, 0);
    VM0;
    BAR;

    for (int t = 0; t < 72; ++t) {
        const int sc = t & 1, ss = sc ^ 1;
        if (t < 71) STG(t + 1, ss);
        DS_AV0(av0, sc);
        DS_BV(bv, sc);
        DS_AV1(av1, sc);
        LGKM(3);                    // av0+bv ready; av1 still landing
        MM(0, 4, av0, bv);
        LGKM(0);                    // av1 ready
        MM(4, 3, av1, bv);
        VM0;                        // tile t+1 staged & landed
        BAR;
    }

    // --- epilogue: per-wave LDS transpose -> coalesced scaled stores ---
    float scale = 50176.0f / (float)(50176 - cB);
    float* ep = (float*)smem + wave * 2080;      // private [32][65] f32
    __syncthreads();
    #pragma unroll
    for (int rr = 0; rr < 4; ++rr) {
        const int r2 = rr & 1;        // 32-channel half of this wave's 64
        const int mh = rr >> 1;       // m half: 0 -> 64 pos, 1 -> 48 pos
        const int nf = mh ? 3 : 4;
        for (int fm2 = 0; fm2 < nf; ++fm2)
            #pragma unroll
            for (int f2 = 0; f2 < 2; ++f2)
                #pragma unroll
                for (int j = 0; j < 4; ++j)
                    ep[(f2 * 16 + lane15) * 65 + fm2 * 16 + grp * 4 + j] =
                        acc[mh * 4 + fm2][r2 * 2 + f2][j];
        __syncthreads();
        {
            int gidx = tix * 224 + wm * 112 + mh * 64 + lane;
            if ((mh == 0 || lane < 48) && gidx < cnt) {
                int m = lst[gidx];
                int n = m / 784, rem = m % 784;
                size_t ob = (size_t)n * 200704 + rem;
                #pragma unroll
                for (int ch = 0; ch < 32; ++ch) {
                    int c = nh * 128 + wn * 64 + r2 * 32 + ch;
                    out[ob + (size_t)c * 784] = ep[ch * 65 + lane] * scale;
                }
            }
        }
        __syncthreads();
    }
#undef AON
#undef STG
#undef DS_AV0
#undef DS_AV1
#undef DS_BV
#undef MM
#undef LGKM
#undef VM0
#undef BAR
}

// ---------------------------------------------------------------------------
extern "C" void kernel_launch(void* const* d_in, const int* in_sizes, int n_in,
                              void* d_out, int out_size, void* d_ws, size_t ws_size,
                              hipStream_t stream) {
    const float* x  = (const float*)d_in[0];
    const float* wl = (const float*)d_in[1];
    const float* wp = (const float*)d_in[2];
    const float* mu = (const float*)d_in[3];
    float* out = (float*)d_out;
    char* ws = (char*)d_ws;

    int* cntB = (int*)ws;                     // = dropped
    int* cntA = (int*)(ws + 4);
    u16* xt = (u16*)(ws + XT_OFF);
    u16* wt = (u16*)(ws + WT_OFF);
    int* listA = (int*)(ws + LISTA_OFF);
    int* listB = (int*)(ws + LISTB_OFF);

    hipMemsetAsync(ws, 0, 8, stream);

    prep_kernel<<<2244, 256, 0, stream>>>(x, wl, wp, mu, xt, wt,
                                          listA, listB, cntB, cntA);
    conv_kernel<<<456, 256, 0, stream>>>((const char*)xt, (const char*)wt,
                                         listA, listB, cntB, out);
}